// Round 1
// baseline (653.181 us; speedup 1.0000x reference)
//
#include <hip/hip_runtime.h>

// MHA: B=2048, N=144, H=4, d=32. qkv [B,144,384] fp32, mask [1,4,144,144] fp32,
// out [B,144,128] fp32. One block per (b,h). bf16 MFMA 16x16x32 (K=32=head_dim).

using short8 = __attribute__((ext_vector_type(8))) short;
using f32x4  = __attribute__((ext_vector_type(4))) float;

#define SEQ   144
#define NH    4
#define HD    32
#define C3    384   // 3*NH*HD
#define OC    128   // NH*HD

#define KSTR  56    // sK row stride (ushort): 112 B = 16B-aligned, conflict-free for b128
#define VSTR  168   // sVT row stride: 336 B = 16B-aligned, conflict-free
#define PSTR  168   // sP row stride

#define LOG2E 1.4426950408889634f
#define SCALE 0.17677669529663687f

__device__ __forceinline__ unsigned short f2bf(float f) {
  unsigned int u = __float_as_uint(f);
  u += 0x7fffu + ((u >> 16) & 1u);   // round-nearest-even to bf16
  return (unsigned short)(u >> 16);
}

__global__ __launch_bounds__(256, 3)
void attn_kernel(const float* __restrict__ qkv,
                 const float* __restrict__ mask,
                 float* __restrict__ out)
{
  __shared__ __align__(16) unsigned short sK [SEQ * KSTR];    // 16128 B
  __shared__ __align__(16) unsigned short sVT[HD  * VSTR];    // 10752 B
  __shared__ __align__(16) unsigned short sP [4][16 * PSTR];  // 21504 B

  const int tid = threadIdx.x;
  const int bid = blockIdx.x;
  const int b = bid >> 2;
  const int h = bid & 3;

  const float* qbase = qkv + (size_t)b * (SEQ * C3) + h * HD;
  const float* kbase = qbase + NH * HD;       // t=1 slice
  const float* vbase = qbase + 2 * NH * HD;   // t=2 slice

  // ---- stage K as bf16 [144][KSTR] ----
  {
    const int n0 = tid >> 4;           // 0..15
    const int d2 = (tid & 15) * 2;     // 0..30
    for (int p = 0; p < 9; ++p) {
      int n = p * 16 + n0;
      float2 kv = *(const float2*)(kbase + (size_t)n * C3 + d2);
      unsigned int pk = (unsigned int)f2bf(kv.x) | ((unsigned int)f2bf(kv.y) << 16);
      *(unsigned int*)&sK[n * KSTR + d2] = pk;
    }
  }
  // ---- stage V transposed: sVT[d][n] = V[n][d], zero-pad cols 144..167 ----
  {
    const int d  = tid & 31;
    const int n0 = tid >> 5;           // 0..7
    for (int p = 0; p < 18; ++p) {
      int n = p * 8 + n0;
      float v = vbase[(size_t)n * C3 + d];
      sVT[d * VSTR + n] = f2bf(v);
    }
    const int r  = tid >> 3;           // 0..31
    const int c0 = tid & 7;
    for (int p = 0; p < 3; ++p)
      sVT[r * VSTR + 144 + c0 + p * 8] = 0;
  }
  __syncthreads();

  const int lane = tid & 63;
  const int wv   = tid >> 6;
  const int m    = lane & 15;   // col in C-layout / m in A-layout / n in B-layout
  const int quad = lane >> 4;

  unsigned short* pbuf = sP[wv];
  // zero-pad this wave's P strip cols 144..159 (stays zero across strips)
  for (int i = 0; i < 4; ++i) {
    int e = lane * 4 + i;              // 0..255
    pbuf[(e >> 4) * PSTR + 144 + (e & 15)] = 0;
  }

  const float qs = SCALE * LOG2E;      // fold softmax scale + log2(e) into Q
  const float* mbase = mask + (size_t)h * SEQ * SEQ;

  for (int s = wv; s < 9; s += 4) {
    // ---- Q fragment (A-layout: lane m holds Q[s*16+m][quad*8 + j]) ----
    short8 afrag;
    {
      const float* qrow = qbase + (size_t)(s * 16 + m) * C3 + quad * 8;
      float4 q0 = *(const float4*)(qrow);
      float4 q1 = *(const float4*)(qrow + 4);
      afrag[0] = (short)f2bf(q0.x * qs); afrag[1] = (short)f2bf(q0.y * qs);
      afrag[2] = (short)f2bf(q0.z * qs); afrag[3] = (short)f2bf(q0.w * qs);
      afrag[4] = (short)f2bf(q1.x * qs); afrag[5] = (short)f2bf(q1.y * qs);
      afrag[6] = (short)f2bf(q1.z * qs); afrag[7] = (short)f2bf(q1.w * qs);
    }

    // ---- S = (Q*scale) K^T + mask  (log2 domain), C-layout regs ----
    float S[9][4];
    for (int nt = 0; nt < 9; ++nt) {
      f32x4 c = {0.f, 0.f, 0.f, 0.f};
      short8 bfrag = *(const short8*)&sK[(nt * 16 + m) * KSTR + quad * 8];
      c = __builtin_amdgcn_mfma_f32_16x16x32_bf16(afrag, bfrag, c, 0, 0, 0);
      const float* mrow = mbase + (size_t)(s * 16 + quad * 4) * SEQ + nt * 16 + m;
      S[nt][0] = c[0] + mrow[0 * SEQ] * LOG2E;
      S[nt][1] = c[1] + mrow[1 * SEQ] * LOG2E;
      S[nt][2] = c[2] + mrow[2 * SEQ] * LOG2E;
      S[nt][3] = c[3] + mrow[3 * SEQ] * LOG2E;
    }

    // ---- softmax: row max + sum via 9-tile reg reduce + 16-lane shfl_xor ----
    float mx[4], l[4];
    for (int r = 0; r < 4; ++r) {
      float v = S[0][r];
      for (int nt = 1; nt < 9; ++nt) v = fmaxf(v, S[nt][r]);
      v = fmaxf(v, __shfl_xor(v, 1));
      v = fmaxf(v, __shfl_xor(v, 2));
      v = fmaxf(v, __shfl_xor(v, 4));
      v = fmaxf(v, __shfl_xor(v, 8));
      mx[r] = v;
      l[r] = 0.f;
    }
    for (int nt = 0; nt < 9; ++nt)
      for (int r = 0; r < 4; ++r) {
        float p = __builtin_amdgcn_exp2f(S[nt][r] - mx[r]);
        S[nt][r] = p;
        l[r] += p;
      }
    for (int r = 0; r < 4; ++r) {
      float v = l[r];
      v += __shfl_xor(v, 1);
      v += __shfl_xor(v, 2);
      v += __shfl_xor(v, 4);
      v += __shfl_xor(v, 8);
      l[r] = 1.0f / v;   // defer normalization to epilogue
    }

    // ---- P -> LDS (C-layout write; A-layout read below). Wave-private. ----
    for (int nt = 0; nt < 9; ++nt)
      for (int r = 0; r < 4; ++r)
        pbuf[(quad * 4 + r) * PSTR + nt * 16 + m] = f2bf(S[nt][r]);

    // ---- O = P V   (K padded to 160; pads are zeroed) ----
    f32x4 acc0 = {0.f, 0.f, 0.f, 0.f}, acc1 = {0.f, 0.f, 0.f, 0.f};
    for (int kt = 0; kt < 5; ++kt) {
      short8 pa = *(const short8*)&pbuf[m * PSTR + kt * 32 + quad * 8];
      short8 b0 = *(const short8*)&sVT[(m)      * VSTR + kt * 32 + quad * 8];
      short8 b1 = *(const short8*)&sVT[(16 + m) * VSTR + kt * 32 + quad * 8];
      acc0 = __builtin_amdgcn_mfma_f32_16x16x32_bf16(pa, b0, acc0, 0, 0, 0);
      acc1 = __builtin_amdgcn_mfma_f32_16x16x32_bf16(pa, b1, acc1, 0, 0, 0);
    }

    // ---- store (C-layout -> out[b][row][h*32 + col]) ----
    float* orow = out + ((size_t)b * SEQ + s * 16 + quad * 4) * OC + h * HD + m;
    for (int r = 0; r < 4; ++r) {
      orow[r * OC]      = acc0[r] * l[r];
      orow[r * OC + 16] = acc1[r] * l[r];
    }
  }
}

extern "C" void kernel_launch(void* const* d_in, const int* in_sizes, int n_in,
                              void* d_out, int out_size, void* d_ws, size_t ws_size,
                              hipStream_t stream) {
  const float* qkv  = (const float*)d_in[0];
  const float* mask = (const float*)d_in[1];
  float* out = (float*)d_out;
  attn_kernel<<<dim3(2048 * NH), dim3(256), 0, stream>>>(qkv, mask, out);
}